// Round 4
// baseline (11333.830 us; speedup 1.0000x reference)
//
#include <hip/hip_runtime.h>
#include <cstdint>
#include <cstddef>

// LSTM_Generator: 3-layer LSTM (H=100) + tanh projection. B=512, T=512, fp32.
//
// R3: R1's wave-specialized structure (ONE w[100] row per thread) + the
// occupancy pin R1 was missing. R1's launch_bounds(1024,1) let the allocator
// target 8 waves/EU -> 64 regs -> full spill; R2 showed >130 live floats per
// thread always spills regardless of pin. So: one row per thread, pinned at
// amdgpu_waves_per_eu(4,4) -> 128-reg budget, w[100]+overhead fits.
//   HG (tid 0..399):   Whh row (quad map r=4u+g), gates(t) + cell update
//   XG (tid 512..911): Wih row + bias, xacc(t+1) one step ahead
//   PF (tid 960..984): float4-prefetch x(t+2) -> LDS double buffer
// One barrier per step; gate exchange via ds_swizzle quad broadcast.

#define HH 100   // hidden
#define G4 400   // 4*H
#define NB 512   // batch
#define NT 512   // timesteps

__device__ __forceinline__ float sigm(float x) {
  return 1.0f / (1.0f + __expf(-x));
}
__device__ __forceinline__ float tanh_(float x) {
  return 1.0f - 2.0f / (__expf(2.0f * x) + 1.0f);
}
// quad broadcasts: every lane of a quad gets lane (quad|k)'s value
__device__ __forceinline__ float qb1(float v) {
  return __int_as_float(__builtin_amdgcn_ds_swizzle(__float_as_int(v), 0x8055));
}
__device__ __forceinline__ float qb2(float v) {
  return __int_as_float(__builtin_amdgcn_ds_swizzle(__float_as_int(v), 0x80AA));
}
__device__ __forceinline__ float qb3(float v) {
  return __int_as_float(__builtin_amdgcn_ds_swizzle(__float_as_int(v), 0x80FF));
}

// -------- layers 1,2: K=100, pipelined wave-specialized --------
__global__ __attribute__((amdgpu_flat_work_group_size(1024, 1024),
                          amdgpu_waves_per_eu(4, 4)))
void lstm_pipe100(
    const float* x,                   // [NB, NT, HH]  (aliases hseq: in-place)
    const float* __restrict__ Wih,    // [G4, HH]
    const float* __restrict__ Whh,    // [G4, HH]
    const float* __restrict__ bias,   // [G4]
    float* hseq)                      // [NB, NT, HH]
{
  const int b = blockIdx.x;
  const int tid = threadIdx.x;

  __shared__ __align__(16) float h_dbuf[2][HH];
  __shared__ __align__(16) float xacc[2][G4];
  __shared__ __align__(16) float x_lds[2][HH];

  const bool isHG = tid < G4;
  const bool isXG = (tid >= 512) && (tid < 512 + G4);
  const int r = isHG ? tid : (tid - 512);     // row slot 0..399
  const int u = r >> 2;                       // hidden unit
  const int g = r & 3;                        // gate: 0=i,1=f,2=g,3=o
  const int row = g * HH + u;                 // row in [4H, H] weight layout

  float w[HH];                                // ONE row: Whh (HG) or Wih (XG)
  float bb = 0.0f;
  if (isHG || isXG) {
    const float* wsrc = isHG ? (Whh + (size_t)row * HH) : (Wih + (size_t)row * HH);
    const float4* w4 = reinterpret_cast<const float4*>(wsrc);
#pragma unroll
    for (int k = 0; k < HH / 4; ++k) {
      float4 v = w4[k];
      w[4 * k] = v.x; w[4 * k + 1] = v.y; w[4 * k + 2] = v.z; w[4 * k + 3] = v.w;
    }
    if (isXG) bb = bias[row];
  }
  if (tid < HH) h_dbuf[0][tid] = 0.0f;
  float c = 0.0f;

  const float* xb = x + (size_t)b * NT * HH;
  float* hb = hseq + (size_t)b * NT * HH;

  // PF (wave 15, 25 lanes): preload x(0), x(1) as float4
  const unsigned pf = (unsigned)(tid - 960);  // 0..63; active if < 25
  if (pf < 25u) {
    reinterpret_cast<float4*>(x_lds[0])[pf] = reinterpret_cast<const float4*>(xb)[pf];
    reinterpret_cast<float4*>(x_lds[1])[pf] = reinterpret_cast<const float4*>(xb + HH)[pf];
  }
  __syncthreads();

  // prologue: xacc(0) from x_lds[0]
  if (isXG) {
    float a0 = 0.f, a1 = 0.f, a2 = 0.f, a3 = 0.f;
    const float4* s4 = reinterpret_cast<const float4*>(x_lds[0]);
#pragma unroll
    for (int k = 0; k < HH / 4; ++k) {
      float4 v = s4[k];
      a0 += v.x * w[4 * k];     a1 += v.y * w[4 * k + 1];
      a2 += v.z * w[4 * k + 2]; a3 += v.w * w[4 * k + 3];
    }
    xacc[0][r] = bb + ((a0 + a1) + (a2 + a3));
  }
  __syncthreads();

  for (int t = 0; t < NT; ++t) {
    const int cur = t & 1, nxt = cur ^ 1;

    // PF: x(t+2) -> x_lds[cur] (consumed by XG at step t+1); barrier-ordered
    if (pf < 25u) {
      int tt = (t + 2 < NT) ? (t + 2) : (NT - 1);
      reinterpret_cast<float4*>(x_lds[cur])[pf] =
          reinterpret_cast<const float4*>(xb + (size_t)tt * HH)[pf];
    }

    // XG: xacc(t+1) = b + Wih . x(t+1), from x_lds[nxt]
    if (isXG) {
      float a0 = 0.f, a1 = 0.f, a2 = 0.f, a3 = 0.f;
      const float4* s4 = reinterpret_cast<const float4*>(x_lds[nxt]);
#pragma unroll
      for (int k = 0; k < HH / 4; ++k) {
        float4 v = s4[k];
        a0 += v.x * w[4 * k];     a1 += v.y * w[4 * k + 1];
        a2 += v.z * w[4 * k + 2]; a3 += v.w * w[4 * k + 3];
      }
      xacc[nxt][r] = bb + ((a0 + a1) + (a2 + a3));
    }

    // HG: gates(t) = xacc(t) + Whh . h(t-1); activation; quad-gather; update
    if (isHG) {
      float xa = xacc[cur][r];
      float a0 = 0.f, a1 = 0.f, a2 = 0.f, a3 = 0.f;
      const float4* s4 = reinterpret_cast<const float4*>(h_dbuf[cur]);
#pragma unroll
      for (int k = 0; k < HH / 4; ++k) {
        float4 v = s4[k];
        a0 += v.x * w[4 * k];     a1 += v.y * w[4 * k + 1];
        a2 += v.z * w[4 * k + 2]; a3 += v.w * w[4 * k + 3];
      }
      float acc = xa + ((a0 + a1) + (a2 + a3));
      float act = (g == 2) ? tanh_(acc) : sigm(acc);
      float fv = qb1(act);
      float gv = qb2(act);
      float ov = qb3(act);
      if (g == 0) {                           // lane 4u owns unit u's c,h
        c = fv * c + act * gv;
        float hv = ov * tanh_(c);
        h_dbuf[nxt][u] = hv;
        hb[(size_t)t * HH + u] = hv;
      }
    }
    __syncthreads();
  }
}

// -------- layer 0: K=1 scalar input --------
__global__ __attribute__((amdgpu_flat_work_group_size(512, 512),
                          amdgpu_waves_per_eu(4, 4)))
void lstm_layer0(
    const float* __restrict__ z,      // [NB, NT, 1]
    const float* __restrict__ Wih,    // [G4, 1]
    const float* __restrict__ Whh,    // [G4, HH]
    const float* __restrict__ bias,   // [G4]
    float* __restrict__ hseq)         // [NB, NT, HH]
{
  const int b = blockIdx.x;
  const int tid = threadIdx.x;

  __shared__ __align__(16) float h_dbuf[2][HH];

  const bool isG = tid < G4;
  const int u = tid >> 2, g = tid & 3;
  const int row = g * HH + u;

  float w[HH];
  float w0 = 0.f, bb = 0.f, c = 0.f;
  if (isG) {
    const float4* w4 = reinterpret_cast<const float4*>(Whh + (size_t)row * HH);
#pragma unroll
    for (int k = 0; k < HH / 4; ++k) {
      float4 v = w4[k];
      w[4 * k] = v.x; w[4 * k + 1] = v.y; w[4 * k + 2] = v.z; w[4 * k + 3] = v.w;
    }
    w0 = Wih[row];
    bb = bias[row];
  }
  if (tid < HH) h_dbuf[0][tid] = 0.0f;

  const float* zb = z + (size_t)b * NT;
  float* hb = hseq + (size_t)b * NT * HH;

  float zc = zb[0];
  __syncthreads();

  for (int t = 0; t < NT; ++t) {
    const int cur = t & 1, nxt = cur ^ 1;
    float zn = (t + 1 < NT) ? zb[t + 1] : 0.f;  // issue early

    if (isG) {
      float a0 = 0.f, a1 = 0.f, a2 = 0.f, a3 = 0.f;
      const float4* h4 = reinterpret_cast<const float4*>(h_dbuf[cur]);
#pragma unroll
      for (int k = 0; k < HH / 4; ++k) {
        float4 v = h4[k];
        a0 += v.x * w[4 * k];     a1 += v.y * w[4 * k + 1];
        a2 += v.z * w[4 * k + 2]; a3 += v.w * w[4 * k + 3];
      }
      float acc = bb + w0 * zc + ((a0 + a1) + (a2 + a3));
      float act = (g == 2) ? tanh_(acc) : sigm(acc);
      float fv = qb1(act);
      float gv = qb2(act);
      float ov = qb3(act);
      if (g == 0) {
        c = fv * c + act * gv;
        float hv = ov * tanh_(c);
        h_dbuf[nxt][u] = hv;
        hb[(size_t)t * HH + u] = hv;
      }
    }
    zc = zn;
    __syncthreads();
  }
}

// -------- projection --------
__global__ __launch_bounds__(256) void proj_kernel(
    const float* __restrict__ hseq,  // [NB*NT, HH]
    const float* __restrict__ Wp,    // [1, HH]
    const float* __restrict__ bp,    // [1]
    float* __restrict__ out)         // [NB*NT]
{
  int idx = blockIdx.x * blockDim.x + threadIdx.x;
  if (idx >= NB * NT) return;
  const float4* h4 = reinterpret_cast<const float4*>(hseq + (size_t)idx * HH);
  const float4* w4 = reinterpret_cast<const float4*>(Wp);
  float a0 = 0.f, a1 = 0.f, a2 = 0.f, a3 = 0.f;
#pragma unroll
  for (int k = 0; k < HH / 4; ++k) {
    float4 h = h4[k];
    float4 w = w4[k];
    a0 += h.x * w.x; a1 += h.y * w.y; a2 += h.z * w.z; a3 += h.w * w.w;
  }
  out[idx] = tanh_(((a0 + a1) + (a2 + a3)) + bp[0]);
}

extern "C" void kernel_launch(void* const* d_in, const int* in_sizes, int n_in,
                              void* d_out, int out_size, void* d_ws, size_t ws_size,
                              hipStream_t stream) {
  const float* z    = (const float*)d_in[0];
  const float* Wih0 = (const float*)d_in[1];
  const float* Whh0 = (const float*)d_in[2];
  const float* b0   = (const float*)d_in[3];
  const float* Wih1 = (const float*)d_in[4];
  const float* Whh1 = (const float*)d_in[5];
  const float* b1   = (const float*)d_in[6];
  const float* Wih2 = (const float*)d_in[7];
  const float* Whh2 = (const float*)d_in[8];
  const float* b2   = (const float*)d_in[9];
  const float* Wp   = (const float*)d_in[10];
  const float* bp   = (const float*)d_in[11];
  float* out = (float*)d_out;

  float* hbuf = (float*)d_ws;   // [NB, NT, HH] fp32 = 52.4 MB

  lstm_layer0<<<NB, 512, 0, stream>>>(z, Wih0, Whh0, b0, hbuf);
  lstm_pipe100<<<NB, 1024, 0, stream>>>(hbuf, Wih1, Whh1, b1, hbuf);
  lstm_pipe100<<<NB, 1024, 0, stream>>>(hbuf, Wih2, Whh2, b2, hbuf);
  proj_kernel<<<(NB * NT + 255) / 256, 256, 0, stream>>>(hbuf, Wp, bp, out);
}

// Round 5
// 4527.426 us; speedup vs baseline: 2.5034x; 2.5034x over previous
//
#include <hip/hip_runtime.h>
#include <cstdint>
#include <cstddef>

// LSTM_Generator: 3-layer LSTM (H=100) + tanh projection. B=512, T=512, fp32.
//
// R4: allocator reality (R0-R3): 512-thr blocks get ~128 VGPRs, 1024-thr
// blocks get 64, and nothing unlocks more. So: Whh row (100 floats) stays in
// regs (fits); Wih is evicted from registers by TIME-TILING the input GEMM:
//   per tile of TT=8 steps:
//     phase A: xw[8][400] = bias + Wih . x(t0..t0+8)  -> LDS
//              (Wih streamed from L2, each float4 reused x8 via acc[8] regs)
//     phase B: 8 recurrent steps, xacc from LDS, quad-swizzle cell update
// Staging x-tile to LDS before any h-write makes in-place hbuf safe.
// 512 threads, 1 block per batch elem, 2 blocks/CU, one round.

#define HH 100   // hidden
#define G4 400   // 4*H
#define NB 512   // batch
#define NT 512   // timesteps
#define TT 8     // time tile

__device__ __forceinline__ float sigm(float x) {
  return 1.0f / (1.0f + __expf(-x));
}
__device__ __forceinline__ float tanh_(float x) {
  return 1.0f - 2.0f / (__expf(2.0f * x) + 1.0f);
}
// quad broadcasts: every lane of a quad gets lane (quad|k)'s value
__device__ __forceinline__ float qb1(float v) {
  return __int_as_float(__builtin_amdgcn_ds_swizzle(__float_as_int(v), 0x8055));
}
__device__ __forceinline__ float qb2(float v) {
  return __int_as_float(__builtin_amdgcn_ds_swizzle(__float_as_int(v), 0x80AA));
}
__device__ __forceinline__ float qb3(float v) {
  return __int_as_float(__builtin_amdgcn_ds_swizzle(__float_as_int(v), 0x80FF));
}

template <int K>
__global__ __launch_bounds__(512, 2) void lstm_tiled(
    const float* x,                   // [NB, NT, K] (K=100: aliases hseq, in-place)
    const float* __restrict__ Wih,    // [G4, K]
    const float* __restrict__ Whh,    // [G4, HH]
    const float* __restrict__ bias,   // [G4]
    float* hseq)                      // [NB, NT, HH]
{
  const int b = blockIdx.x;
  const int tid = threadIdx.x;

  __shared__ __align__(16) float xw_lds[TT * G4];   // 12.8 KB
  __shared__ __align__(16) float x_lds[TT * K];     // 3.2 KB (K=100) / 32 B (K=1)
  __shared__ __align__(16) float h_dbuf[2][HH];

  const bool isG = tid < G4;
  const int u = tid >> 2, g = tid & 3;     // quad map: slot r=4u+g
  const int row = g * HH + u;              // row in [4H] weight layout

  float4 whh4[HH / 4];                     // Whh row: 100 floats, resident
  float bb = 0.0f, c = 0.0f, wih1 = 0.0f;
  if (isG) {
    const float4* w4 = reinterpret_cast<const float4*>(Whh + (size_t)row * HH);
#pragma unroll
    for (int k = 0; k < HH / 4; ++k) whh4[k] = w4[k];
    bb = bias[row];
    if constexpr (K == 1) wih1 = Wih[row];
  }
  if (tid < HH) h_dbuf[0][tid] = 0.0f;

  const float* xb = x + (size_t)b * NT * K;
  float* hb = hseq + (size_t)b * NT * HH;
  __syncthreads();

  for (int tile = 0; tile < NT / TT; ++tile) {
    const int t0 = tile * TT;

    // ---- stage x tile: contiguous TT*K floats (in-place safe: h-writes of
    // these rows happen only in phase B, after the barrier) ----
    {
      const float4* src = reinterpret_cast<const float4*>(xb + (size_t)t0 * K);
      float4* dst = reinterpret_cast<float4*>(x_lds);
      for (int i = tid; i < (TT * K) / 4; i += 512) dst[i] = src[i];
    }
    __syncthreads();

    // ---- phase A: xw[tt][r] = bias + Wih(row) . x(t0+tt) ----
    if (isG) {
      float acc[TT];
#pragma unroll
      for (int tt = 0; tt < TT; ++tt) acc[tt] = bb;
      if constexpr (K == 1) {
#pragma unroll
        for (int tt = 0; tt < TT; ++tt) acc[tt] += wih1 * x_lds[tt];
      } else {
        const float4* wi4 = reinterpret_cast<const float4*>(Wih + (size_t)row * K);
#pragma unroll
        for (int k4 = 0; k4 < K / 4; ++k4) {
          float4 w = wi4[k4];            // L2 load, reused x TT
#pragma unroll
          for (int tt = 0; tt < TT; ++tt) {
            const float* xr = x_lds + tt * K + 4 * k4;  // uniform -> broadcast
            acc[tt] += w.x * xr[0] + w.y * xr[1] + w.z * xr[2] + w.w * xr[3];
          }
        }
      }
#pragma unroll
      for (int tt = 0; tt < TT; ++tt) xw_lds[tt * G4 + tid] = acc[tt];
    }
    __syncthreads();

    // ---- phase B: TT recurrent steps ----
    for (int s = 0; s < TT; ++s) {
      const int cur = s & 1, nxt = cur ^ 1;   // t0 even -> parity consistent
      if (isG) {
        float xa = xw_lds[s * G4 + tid];
        float a0 = 0.f, a1 = 0.f, a2 = 0.f, a3 = 0.f;
        const float4* h4 = reinterpret_cast<const float4*>(h_dbuf[cur]);
#pragma unroll
        for (int k = 0; k < HH / 4; ++k) {
          float4 v = h4[k];                   // uniform -> broadcast
          a0 += v.x * whh4[k].x; a1 += v.y * whh4[k].y;
          a2 += v.z * whh4[k].z; a3 += v.w * whh4[k].w;
        }
        float accv = xa + ((a0 + a1) + (a2 + a3));
        float act = (g == 2) ? tanh_(accv) : sigm(accv);
        float fv = qb1(act);
        float gv = qb2(act);
        float ov = qb3(act);
        if (g == 0) {                         // lane 4u owns unit u's c,h
          c = fv * c + act * gv;
          float hv = ov * tanh_(c);
          h_dbuf[nxt][u] = hv;
          hb[(size_t)(t0 + s) * HH + u] = hv;
        }
      }
      __syncthreads();
    }
  }
}

// -------- projection --------
__global__ __launch_bounds__(256) void proj_kernel(
    const float* __restrict__ hseq,  // [NB*NT, HH]
    const float* __restrict__ Wp,    // [1, HH]
    const float* __restrict__ bp,    // [1]
    float* __restrict__ out)         // [NB*NT]
{
  int idx = blockIdx.x * blockDim.x + threadIdx.x;
  if (idx >= NB * NT) return;
  const float4* h4 = reinterpret_cast<const float4*>(hseq + (size_t)idx * HH);
  const float4* w4 = reinterpret_cast<const float4*>(Wp);
  float a0 = 0.f, a1 = 0.f, a2 = 0.f, a3 = 0.f;
#pragma unroll
  for (int k = 0; k < HH / 4; ++k) {
    float4 h = h4[k];
    float4 w = w4[k];
    a0 += h.x * w.x; a1 += h.y * w.y; a2 += h.z * w.z; a3 += h.w * w.w;
  }
  out[idx] = tanh_(((a0 + a1) + (a2 + a3)) + bp[0]);
}

extern "C" void kernel_launch(void* const* d_in, const int* in_sizes, int n_in,
                              void* d_out, int out_size, void* d_ws, size_t ws_size,
                              hipStream_t stream) {
  const float* z    = (const float*)d_in[0];
  const float* Wih0 = (const float*)d_in[1];
  const float* Whh0 = (const float*)d_in[2];
  const float* b0   = (const float*)d_in[3];
  const float* Wih1 = (const float*)d_in[4];
  const float* Whh1 = (const float*)d_in[5];
  const float* b1   = (const float*)d_in[6];
  const float* Wih2 = (const float*)d_in[7];
  const float* Whh2 = (const float*)d_in[8];
  const float* b2   = (const float*)d_in[9];
  const float* Wp   = (const float*)d_in[10];
  const float* bp   = (const float*)d_in[11];
  float* out = (float*)d_out;

  float* hbuf = (float*)d_ws;   // [NB, NT, HH] fp32 = 104.9 MB

  lstm_tiled<1><<<NB, 512, 0, stream>>>(z, Wih0, Whh0, b0, hbuf);
  lstm_tiled<HH><<<NB, 512, 0, stream>>>(hbuf, Wih1, Whh1, b1, hbuf);
  lstm_tiled<HH><<<NB, 512, 0, stream>>>(hbuf, Wih2, Whh2, b2, hbuf);
  proj_kernel<<<(NB * NT + 255) / 256, 256, 0, stream>>>(hbuf, Wp, bp, out);
}